// Round 1
// baseline (109.883 us; speedup 1.0000x reference)
//
#include <hip/hip_runtime.h>

// IndRNN encoder/decoder net, algebraically collapsed:
// predict uses only decoder-batch 0 => only last[0] = y_enc1[t=0, b=4095]
// => encoder needed only at (t=0, b=4095), recurrent u terms vanish at t=0.
// Pipeline: last0 (matvec) -> G[20] (matvec + scan) -> H1[20] (20-matvec GEMM
// + scan) -> predict (40-way reduction). ~12.6 MB reads, ~46 MFLOP.

#define HID 1024
#define TSTEPS 20

__device__ __forceinline__ float wred(float v) {
#pragma unroll
    for (int off = 32; off > 0; off >>= 1) v += __shfl_down(v, off, 64);
    return v;  // valid in lane 0
}

// K1: v0 = relu(enc_w0 @ x[0,4095] + enc_b0); last0 = relu(enc_w1 @ v0 + enc_b1)
// grid 256 x 256: wave per output row h (4 rows/block)
__global__ __launch_bounds__(256) void k_enc(
    const float* __restrict__ x, const float* __restrict__ w0,
    const float* __restrict__ b0, const float* __restrict__ w1,
    const float* __restrict__ b1, float* __restrict__ last0) {
    __shared__ float v0s[HID];
    const float x0 = x[(0 * 4096 + 4095) * 2 + 0];
    const float x1 = x[(0 * 4096 + 4095) * 2 + 1];
    for (int i = threadIdx.x; i < HID; i += 256)
        v0s[i] = fmaxf(fmaf(w0[2 * i], x0, fmaf(w0[2 * i + 1], x1, b0[i])), 0.f);
    __syncthreads();
    const int wave = threadIdx.x >> 6, lane = threadIdx.x & 63;
    const int h = blockIdx.x * 4 + wave;
    const float4* wrow = (const float4*)(w1 + h * HID);
    float s = 0.f;
#pragma unroll
    for (int k = 0; k < 4; ++k) {
        float4 wv = wrow[lane * 4 + k];
        int ib = lane * 16 + k * 4;
        s = fmaf(wv.x, v0s[ib + 0], s);
        s = fmaf(wv.y, v0s[ib + 1], s);
        s = fmaf(wv.z, v0s[ib + 2], s);
        s = fmaf(wv.w, v0s[ib + 3], s);
    }
    s = wred(s);
    if (lane == 0) last0[h] = fmaxf(s + b1[h], 0.f);
}

// K2: p = dec_w0 @ last0 + dec_b0; G[t][h] = scan relu(p + u0*g), t=0..19
__global__ __launch_bounds__(256) void k_dec0(
    const float* __restrict__ last0, const float* __restrict__ w0,
    const float* __restrict__ u0, const float* __restrict__ b0,
    float* __restrict__ G) {
    __shared__ float l0[HID];
    for (int i = threadIdx.x; i < HID; i += 256) l0[i] = last0[i];
    __syncthreads();
    const int wave = threadIdx.x >> 6, lane = threadIdx.x & 63;
    const int h = blockIdx.x * 4 + wave;
    const float4* wrow = (const float4*)(w0 + h * HID);
    float s = 0.f;
#pragma unroll
    for (int k = 0; k < 4; ++k) {
        float4 wv = wrow[lane * 4 + k];
        int ib = lane * 16 + k * 4;
        s = fmaf(wv.x, l0[ib + 0], s);
        s = fmaf(wv.y, l0[ib + 1], s);
        s = fmaf(wv.z, l0[ib + 2], s);
        s = fmaf(wv.w, l0[ib + 3], s);
    }
    s = wred(s);
    if (lane == 0) {
        const float p = s + b0[h], uu = u0[h];
        float g = 0.f;
#pragma unroll
        for (int t = 0; t < TSTEPS; ++t) {
            g = fmaxf(fmaf(uu, g, p), 0.f);
            G[t * HID + h] = g;
        }
    }
}

// K3: Q[t] = dec_w1 @ G[t] + dec_b1; H1[t][h] = scan relu(q + u1*h1)
// wave per row h; W row chunk held in regs, reused across all 20 t.
__global__ __launch_bounds__(256) void k_dec1(
    const float* __restrict__ G, const float* __restrict__ w1,
    const float* __restrict__ u1, const float* __restrict__ b1,
    float* __restrict__ H1) {
    const int wave = threadIdx.x >> 6, lane = threadIdx.x & 63;
    const int h = blockIdx.x * 4 + wave;
    const float4* wrow = (const float4*)(w1 + h * HID);
    float4 w[4];
#pragma unroll
    for (int k = 0; k < 4; ++k) w[k] = wrow[lane * 4 + k];
    const float uu = u1[h], bb = b1[h];
    float hh = 0.f;
    for (int t = 0; t < TSTEPS; ++t) {
        const float4* gt = (const float4*)(G + t * HID);
        float s = 0.f;
#pragma unroll
        for (int k = 0; k < 4; ++k) {
            float4 gv = gt[lane * 4 + k];
            s = fmaf(w[k].x, gv.x, s);
            s = fmaf(w[k].y, gv.y, s);
            s = fmaf(w[k].z, gv.z, s);
            s = fmaf(w[k].w, gv.w, s);
        }
        s = wred(s);  // true sum in lane 0 only; hh only meaningful there
        hh = fmaxf(fmaf(uu, hh, s + bb), 0.f);
        if (lane == 0) H1[t * HID + h] = hh;
    }
}

// K4: predict[t][j] = out_w[j] . H1[t] + out_b[j]; block per t
__global__ __launch_bounds__(256) void k_out(
    const float* __restrict__ H1, const float* __restrict__ ow,
    const float* __restrict__ ob, float* __restrict__ out) {
    const int t = blockIdx.x, tid = threadIdx.x;
    const float4* hv = (const float4*)(H1 + t * HID);
    const float4* wa = (const float4*)(ow);
    const float4* wb = (const float4*)(ow + HID);
    float4 h4 = hv[tid], a = wa[tid], b = wb[tid];
    float s0 = h4.x * a.x + h4.y * a.y + h4.z * a.z + h4.w * a.w;
    float s1 = h4.x * b.x + h4.y * b.y + h4.z * b.z + h4.w * b.w;
    s0 = wred(s0);
    s1 = wred(s1);
    __shared__ float p[8];
    const int wave = tid >> 6, lane = tid & 63;
    if (lane == 0) {
        p[wave * 2 + 0] = s0;
        p[wave * 2 + 1] = s1;
    }
    __syncthreads();
    if (tid == 0) out[t * 2 + 0] = p[0] + p[2] + p[4] + p[6] + ob[0];
    if (tid == 1) out[t * 2 + 1] = p[1] + p[3] + p[5] + p[7] + ob[1];
}

extern "C" void kernel_launch(void* const* d_in, const int* in_sizes, int n_in,
                              void* d_out, int out_size, void* d_ws, size_t ws_size,
                              hipStream_t stream) {
    const float* x      = (const float*)d_in[0];
    const float* enc_w0 = (const float*)d_in[1];
    // d_in[2] = enc_u0 — provably unused (encoder only needed at t=0)
    const float* enc_b0 = (const float*)d_in[3];
    const float* enc_w1 = (const float*)d_in[4];
    // d_in[5] = enc_u1 — unused
    const float* enc_b1 = (const float*)d_in[6];
    const float* dec_w0 = (const float*)d_in[7];
    const float* dec_u0 = (const float*)d_in[8];
    const float* dec_b0 = (const float*)d_in[9];
    const float* dec_w1 = (const float*)d_in[10];
    const float* dec_u1 = (const float*)d_in[11];
    const float* dec_b1 = (const float*)d_in[12];
    const float* out_w  = (const float*)d_in[13];
    const float* out_b  = (const float*)d_in[14];
    float* out = (float*)d_out;

    float* ws    = (float*)d_ws;
    float* last0 = ws;                        // 1024
    float* G     = ws + HID;                  // 20*1024
    float* H1    = ws + HID + TSTEPS * HID;   // 20*1024  (~168 KB total)

    k_enc<<<256, 256, 0, stream>>>(x, enc_w0, enc_b0, enc_w1, enc_b1, last0);
    k_dec0<<<256, 256, 0, stream>>>(last0, dec_w0, dec_u0, dec_b0, G);
    k_dec1<<<256, 256, 0, stream>>>(G, dec_w1, dec_u1, dec_b1, H1);
    k_out<<<20, 256, 0, stream>>>(H1, out_w, out_b, out);
}